// Round 6
// baseline (253.776 us; speedup 1.0000x reference)
//
#include <hip/hip_runtime.h>
#include <hip/hip_bf16.h>

#define DIN 128
#define NEG_SLOPE 0.2f
#define PTILE 1024        // edges per partition tile (halved: more parallelism)
#define FCAP 8192         // fine-kernel LDS edge capacity (mean 4096, sigma~64)
#define CVT_BLKS 289      // blocks of cvt work in the merged cvt+hist kernel

typedef __attribute__((ext_vector_type(8))) short bf16x8;   // 8 bf16 = 4 VGPRs
typedef __attribute__((ext_vector_type(8))) unsigned short u16x8;
typedef __attribute__((ext_vector_type(4))) float f32x4;
typedef __attribute__((ext_vector_type(2))) float f32x2;
typedef __attribute__((ext_vector_type(4))) unsigned int u32x4;

__device__ __forceinline__ ushort f2bf(float f) {
  unsigned u = __float_as_uint(f);
  u += 0x7FFFu + ((u >> 16) & 1u);   // round-to-nearest-even
  return (ushort)(u >> 16);
}
// unpack 2 packed bf16 (one dword) -> f32x2 {elem0, elem1}
__device__ __forceinline__ f32x2 bfpair(unsigned u) {
  f32x2 r;
  r.x = __uint_as_float(u << 16);
  r.y = __uint_as_float(u & 0xFFFF0000u);
  return r;
}

// DPP-based sum across each 16-lane row (all lanes get the total).
template <int CTRL>
__device__ __forceinline__ float dppadd(float x) {
  int v = __builtin_amdgcn_update_dpp(0, __float_as_int(x), CTRL, 0xf, 0xf, true);
  return x + __int_as_float(v);
}
__device__ __forceinline__ float red16(float t) {
  t = dppadd<0xB1>(t);    // quad_perm [1,0,3,2]  : + lane^1
  t = dppadd<0x4E>(t);    // quad_perm [2,3,0,1]  : + lane^2
  t = dppadd<0x141>(t);   // row_half_mirror      : + lane^7  (xor4-equiv)
  t = dppadd<0x140>(t);   // row_mirror           : + lane^15 (xor8-equiv)
  return t;
}

// ---------------------------------------------------------------------------
// merged prep: blocks [0,CVT_BLKS) convert weights -> bf16 transposed;
// blocks [CVT_BLKS,...) build the 256-bucket dst histogram (bucket=dst>>8).
// ghist+cursor0 zeroed by one hipMemsetAsync before this kernel.
// ---------------------------------------------------------------------------
__global__ __launch_bounds__(256) void cvt_hist_kernel(
    const float* __restrict__ Wl, const float* __restrict__ Wr,
    const float* __restrict__ W1, const float* __restrict__ W2,
    const float* __restrict__ W3,
    ushort* __restrict__ WlT, ushort* __restrict__ WrT,
    ushort* __restrict__ W1T, ushort* __restrict__ W2T,
    ushort* __restrict__ W3T,
    const int* __restrict__ ei, int* __restrict__ ghist, int E) {
  if (blockIdx.x < CVT_BLKS) {
    int i = blockIdx.x * 256 + threadIdx.x;
    if (i < 16384) {
      int k = i >> 7, c = i & 127; WlT[c * 128 + k] = f2bf(Wl[i]);
    } else if (i < 32768) {
      int j = i - 16384; int k = j >> 7, c = j & 127; WrT[c * 128 + k] = f2bf(Wr[j]);
    } else if (i < 49152) {
      int j = i - 32768; int k = j >> 7, c = j & 127; W1T[c * 128 + k] = f2bf(W1[j]);
    } else if (i < 65536) {
      int j = i - 49152; int k = j >> 7, c = j & 127; W2T[c * 128 + k] = f2bf(W2[j]);
    } else if (i < 73728) {
      int j = i - 65536; int k = j >> 6, c = j & 63; W3T[c * 128 + k] = f2bf(W3[j]);
    }
  } else {
    __shared__ int h[256];
    h[threadIdx.x] = 0;
    __syncthreads();
    int tile = blockIdx.x - CVT_BLKS;
    for (int e = tile * PTILE + threadIdx.x;
         e < min(E, (tile + 1) * PTILE); e += 256)
      atomicAdd(&h[ei[E + e] >> 8], 1);
    __syncthreads();
    if (h[threadIdx.x] > 0) atomicAdd(&ghist[threadIdx.x], h[threadIdx.x]);
  }
}

// ---------------------------------------------------------------------------
// MEGA kernel: blocks [0,nblk_lin) run the lin_lr MFMA GEMM; the rest run
// the partition pass. scan_small is GONE: each partition block redundantly
// excl-scans ghist[256] in LDS (parallel, ~1KB) and reserves bucket slots
// via atomicAdd on the zeroed cursor0.
// ---------------------------------------------------------------------------
__global__ __launch_bounds__(256) void lin_partition_kernel(
    const float* __restrict__ x,
    const ushort* __restrict__ WlT, const float* __restrict__ bl,
    const ushort* __restrict__ WrT, const float* __restrict__ br,
    ushort* __restrict__ xl, ushort* __restrict__ xr, int n, int nblk_lin,
    const int* __restrict__ ei, unsigned* __restrict__ part,
    const int* __restrict__ ghist, int* __restrict__ cursor0, int E) {
  if ((int)blockIdx.x < nblk_lin) {
    // ---- lin_lr: xl = x@Wl+bl ; xr = x@Wr+br (bf16 out) ----
    const int tid = threadIdx.x;
    const int wv = tid >> 6, lane = tid & 63;
    const int m = lane & 15, quad = lane >> 4;
    const int colbase = (wv & 1) * 64;
    const int nodew = blockIdx.x * 32 + (wv >> 1) * 16;
    int arow = nodew + m; if (arow >= n) arow = n - 1;
    f32x4 accl[4], accr[4];
#pragma unroll
    for (int nt = 0; nt < 4; nt++) { accl[nt] = (f32x4){0,0,0,0}; accr[nt] = (f32x4){0,0,0,0}; }
#pragma unroll
    for (int kk = 0; kk < 4; kk++) {
      int k0 = kk * 32 + quad * 8;
      const float4* xp = (const float4*)(x + (long)arow * 128 + k0);
      float4 x0 = xp[0], x1 = xp[1];
      bf16x8 af;
      af[0] = (short)f2bf(x0.x); af[1] = (short)f2bf(x0.y);
      af[2] = (short)f2bf(x0.z); af[3] = (short)f2bf(x0.w);
      af[4] = (short)f2bf(x1.x); af[5] = (short)f2bf(x1.y);
      af[6] = (short)f2bf(x1.z); af[7] = (short)f2bf(x1.w);
#pragma unroll
      for (int nt = 0; nt < 4; nt++) {
        int brow = colbase + nt * 16 + m;
        bf16x8 bl8 = *(const bf16x8*)(WlT + brow * 128 + k0);
        bf16x8 br8 = *(const bf16x8*)(WrT + brow * 128 + k0);
        accl[nt] = __builtin_amdgcn_mfma_f32_16x16x32_bf16(af, bl8, accl[nt], 0, 0, 0);
        accr[nt] = __builtin_amdgcn_mfma_f32_16x16x32_bf16(af, br8, accr[nt], 0, 0, 0);
      }
    }
#pragma unroll
    for (int nt = 0; nt < 4; nt++) {
      int col = colbase + nt * 16 + m;
      float vbl = bl[col], vbr = br[col];
#pragma unroll
      for (int r = 0; r < 4; r++) {
        int node = nodew + quad * 4 + r;
        if (node < n) {
          xl[(long)node * 128 + col] = f2bf(accl[nt][r] + vbl);
          xr[(long)node * 128 + col] = f2bf(accr[nt][r] + vbr);
        }
      }
    }
  } else {
    // ---- partition: tile -> LDS bucket-grouped reorder -> dense runs ----
    __shared__ int hist[256], pref[256], sexcl[256], curs[256], gbase[256],
                   gsc[256];
    const int tid = threadIdx.x;
    const int gv0 = ghist[tid];
    gsc[tid] = gv0;
    hist[tid] = 0;
    __syncthreads();
    __shared__ unsigned buf[PTILE];
    const int tile0 = ((int)blockIdx.x - nblk_lin) * PTILE;
    const int tcount = min(PTILE, E - tile0);
    unsigned pk[PTILE / 256];
    int cnt = 0;
    for (int i = tid; i < tcount; i += 256) {
      int e = tile0 + i;
      int s = ei[e], d = ei[E + e];
      unsigned p = ((unsigned)d << 16) | (unsigned)s;
      pk[cnt++] = p;
      atomicAdd(&hist[d >> 8], 1);
    }
    __syncthreads();
    int v = hist[tid];
    pref[tid] = v;
    __syncthreads();
    // joint scan: local tile hist AND global bucket hist in the same rounds
    for (int d = 1; d < 256; d <<= 1) {
      int t1 = (tid >= d) ? pref[tid - d] : 0;
      int t2 = (tid >= d) ? gsc[tid - d] : 0;
      __syncthreads();
      pref[tid] += t1;
      gsc[tid] += t2;
      __syncthreads();
    }
    int exc = pref[tid] - v;
    sexcl[tid] = exc;
    curs[tid] = exc;
    gbase[tid] = (gsc[tid] - gv0) + ((v > 0) ? atomicAdd(&cursor0[tid], v) : 0);
    __syncthreads();
    for (int j = 0; j < cnt; j++) {
      int b = pk[j] >> 24;
      int pos = atomicAdd(&curs[b], 1);
      buf[pos] = pk[j];
    }
    __syncthreads();
    for (int i = tid; i < tcount; i += 256) {
      unsigned p = buf[i];
      int b = p >> 24;
      part[gbase[b] + (i - sexcl[b])] = p;
    }
  }
}

// per-bucket: node hist + scan -> offsets; LDS reorder -> coalesced ssrc
// (ushort: src < 65536). 512 threads. Bucket span derived from an in-block
// scan of ghist (cum[] is gone).
__global__ __launch_bounds__(512) void fine_kernel(
    const unsigned* __restrict__ part, const int* __restrict__ ghist,
    int* __restrict__ offsets, ushort* __restrict__ ssrc,
    int N, int E, int nbuck) {
  __shared__ int hist[256], pref[256], curs[256], gsc[256];
  __shared__ unsigned buf[FCAP], buf2[FCAP];
  const int tid = threadIdx.x;
  const int b = blockIdx.x;
  if (tid < 256) {
    gsc[tid] = ghist[tid];
    hist[tid] = 0;
  }
  __syncthreads();
  for (int d = 1; d < 256; d <<= 1) {
    int t = (tid >= d && tid < 256) ? gsc[tid - d] : 0;
    __syncthreads();
    if (tid < 256) gsc[tid] += t;
    __syncthreads();
  }
  const int seg0 = (b == 0) ? 0 : gsc[b - 1];       // inclusive scan -> base
  const int len = min(gsc[b] - seg0, FCAP);
  for (int i = tid; i < len; i += 512) {
    unsigned p = part[seg0 + i];
    buf[i] = p;
    atomicAdd(&hist[(p >> 16) & 255], 1);
  }
  __syncthreads();
  int v = (tid < 256) ? hist[tid] : 0;
  if (tid < 256) pref[tid] = v;
  __syncthreads();
  for (int d = 1; d < 256; d <<= 1) {
    int t = (tid >= d && tid < 256) ? pref[tid - d] : 0;
    __syncthreads();
    if (tid < 256) pref[tid] += t;
    __syncthreads();
  }
  if (tid < 256) {
    int exc = pref[tid] - v;
    curs[tid] = exc;
    int node = b * 256 + tid;
    if (node < N) offsets[node] = seg0 + exc;
  }
  if (b == nbuck - 1 && tid == 0) offsets[N] = E;
  __syncthreads();
  for (int i = tid; i < len; i += 512) {
    unsigned p = buf[i];
    int pos = atomicAdd(&curs[(p >> 16) & 255], 1);
    buf2[pos] = p;
  }
  __syncthreads();
  for (int i = tid; i < len; i += 512)
    ssrc[seg0 + i] = (ushort)(buf2[i] & 0xFFFFu);
}

// ---------------------------------------------------------------------------
// FUSED GATv2 aggregation + 3-layer MLP. Block = 32 nodes: phase A, each of
// the 4 waves runs the (unchanged R5) per-node edge loop for 8 nodes,
// writing h rows to LDS; phase B is the MFMA MLP reading h from LDS.
// Deletes the 25.6MB h HBM round-trip + one kernel launch.
// ---------------------------------------------------------------------------
#define LDSP 136
__global__ __launch_bounds__(256) void node_mlp_kernel(
    const ushort* __restrict__ xl, const ushort* __restrict__ xr,
    const float* __restrict__ att, const float* __restrict__ bg,
    const int* __restrict__ offsets, const ushort* __restrict__ ssrc,
    const ushort* __restrict__ W1T, const float* __restrict__ b1,
    const ushort* __restrict__ W2T, const float* __restrict__ b2,
    const ushort* __restrict__ W3T, const float* __restrict__ b3,
    float* __restrict__ out, int n) {
  __shared__ ushort hst[32][LDSP];
  __shared__ ushort act[32][LDSP];
  const int tid = threadIdx.x;
  const int wv = tid >> 6, lane = tid & 63;
  // ===================== phase A: per-node GATv2 aggregation ==============
  {
    const int eg = lane >> 4, sl = lane & 15;
    const ushort* __restrict__ xls = xl + sl * 8;   // lane-fixed column base
    f32x2 a06[4], a04[4], gvb[4];
    {
      const float4* ap = (const float4*)(att + sl * 8);
      float4 a0 = ap[0], a1 = ap[1];
      f32x2 av[4] = {{a0.x, a0.y}, {a0.z, a0.w}, {a1.x, a1.y}, {a1.z, a1.w}};
#pragma unroll
      for (int jp = 0; jp < 4; jp++) {
        a06[jp] = 0.6f * av[jp];
        a04[jp] = 0.4f * av[jp];
      }
      const float4* bp = (const float4*)(bg + sl * 8);
      float4 g0 = bp[0], g1 = bp[1];
      gvb[0] = (f32x2){g0.x, g0.y}; gvb[1] = (f32x2){g0.z, g0.w};
      gvb[2] = (f32x2){g1.x, g1.y}; gvb[3] = (f32x2){g1.z, g1.w};
    }
    for (int nn = 0; nn < 8; nn++) {
      const int node = (int)blockIdx.x * 32 + wv * 8 + nn;
      if (node >= n) continue;      // wave-uniform
      const int beg = offsets[node];
      const int end = offsets[node + 1];
      const int last = end - 1;
      int ia0 = beg + 2 * eg;
      int sa  = (int)ssrc[min(ia0, last)];
      int sb  = (int)ssrc[min(ia0 + 1, last)];
      int sa2 = (int)ssrc[min(ia0 + 8, last)];
      int sb2 = (int)ssrc[min(ia0 + 9, last)];
      u32x4 uva = *(const u32x4*)(xls + (long)sa * 128);
      u32x4 uvb = *(const u32x4*)(xls + (long)sb * 128);
      f32x2 r2[4], acc2[4];
      u32x4 rv = *(const u32x4*)(xr + (long)node * 128 + sl * 8);
      u32x4 lv = *(const u32x4*)(xls + (long)node * 128);
      float denom;
      {
        f32x2 t1 = {0.f, 0.f}, t2 = {0.f, 0.f};
        f32x2 l2[4];
#pragma unroll
        for (int jp = 0; jp < 4; jp++) {
          r2[jp] = bfpair(rv[jp]);
          l2[jp] = bfpair(lv[jp]);
          f32x2 v = l2[jp] + r2[jp];
          t1 += a06[jp] * v;
          t2 += a04[jp] * __builtin_elementwise_abs(v);
        }
        float t = red16(t1.x + t1.y + t2.x + t2.y);
        float es = __expf(t);             // self-loop weight
        denom = (eg == 0) ? es : 0.f;
#pragma unroll
        for (int jp = 0; jp < 4; jp++)
          acc2[jp] = (eg == 0) ? es * l2[jp] : (f32x2){0.f, 0.f};
      }
      for (int p = beg; p < end; p += 8) {
        u32x4 ca = uva, cb = uvb;
        int ia = p + 2 * eg;
        bool cva = ia < end, cvb = ia + 1 < end;
        uva = *(const u32x4*)(xls + (long)sa2 * 128);
        uvb = *(const u32x4*)(xls + (long)sb2 * 128);
        int ian = p + 16 + 2 * eg;
        sa2 = (int)ssrc[min(ian, last)];
        sb2 = (int)ssrc[min(ian + 1, last)];
        f32x2 ua2[4], ub2[4];
        f32x2 ta1 = {0.f, 0.f}, ta2 = {0.f, 0.f};
        f32x2 tb1 = {0.f, 0.f}, tb2 = {0.f, 0.f};
#pragma unroll
        for (int jp = 0; jp < 4; jp++) {
          ua2[jp] = bfpair(ca[jp]);
          ub2[jp] = bfpair(cb[jp]);
          f32x2 va2 = ua2[jp] + r2[jp];
          f32x2 vb2 = ub2[jp] + r2[jp];
          ta1 += a06[jp] * va2;
          ta2 += a04[jp] * __builtin_elementwise_abs(va2);
          tb1 += a06[jp] * vb2;
          tb2 += a04[jp] * __builtin_elementwise_abs(vb2);
        }
        float ta = red16(ta1.x + ta1.y + ta2.x + ta2.y);
        float tb = red16(tb1.x + tb1.y + tb2.x + tb2.y);
        float ea = cva ? __expf(ta) : 0.f;
        float eb = cvb ? __expf(tb) : 0.f;
        denom += ea + eb;
#pragma unroll
        for (int jp = 0; jp < 4; jp++)
          acc2[jp] += ea * ua2[jp] + eb * ub2[jp];
      }
#pragma unroll
      for (int jp = 0; jp < 4; jp++) {
        acc2[jp].x += __shfl_xor(acc2[jp].x, 16);
        acc2[jp].y += __shfl_xor(acc2[jp].y, 16);
        acc2[jp].x += __shfl_xor(acc2[jp].x, 32);
        acc2[jp].y += __shfl_xor(acc2[jp].y, 32);
      }
      denom += __shfl_xor(denom, 16);
      denom += __shfl_xor(denom, 32);
      if (eg == 0) {
        float inv = 1.0f / denom;
        u16x8 o;
#pragma unroll
        for (int jp = 0; jp < 4; jp++) {
          f32x2 hv = acc2[jp] * inv + gvb[jp];
          o[2 * jp]     = f2bf(hv.x);
          o[2 * jp + 1] = f2bf(hv.y);
        }
        *(u16x8*)(&hst[wv * 8 + nn][sl * 8]) = o;
      }
    }
  }
  __syncthreads();
  // ===================== phase B: 3-layer MFMA MLP ========================
  const int m = lane & 15, quad = lane >> 4;
  const int half = wv & 1, ng = wv >> 1;
  const int colbase = half * 64;
  const int nodew = (int)blockIdx.x * 32 + ng * 16;
  f32x4 acc[4];
#pragma unroll
  for (int nt = 0; nt < 4; nt++) acc[nt] = (f32x4){0,0,0,0};
#pragma unroll
  for (int kk = 0; kk < 4; kk++) {
    int k0 = kk * 32 + quad * 8;
    bf16x8 af = *(const bf16x8*)(&hst[ng * 16 + m][k0]);
#pragma unroll
    for (int nt = 0; nt < 4; nt++) {
      bf16x8 b8 = *(const bf16x8*)(W1T + (colbase + nt * 16 + m) * 128 + k0);
      acc[nt] = __builtin_amdgcn_mfma_f32_16x16x32_bf16(af, b8, acc[nt], 0, 0, 0);
    }
  }
#pragma unroll
  for (int nt = 0; nt < 4; nt++) {
    int col = colbase + nt * 16 + m;
    float b = b1[col];
#pragma unroll
    for (int r = 0; r < 4; r++)
      act[ng * 16 + quad * 4 + r][col] = f2bf(fmaxf(acc[nt][r] + b, 0.f));
  }
  __syncthreads();
#pragma unroll
  for (int nt = 0; nt < 4; nt++) acc[nt] = (f32x4){0,0,0,0};
#pragma unroll
  for (int kk = 0; kk < 4; kk++) {
    int k0 = kk * 32 + quad * 8;
    bf16x8 af = *(const bf16x8*)(&act[ng * 16 + m][k0]);
#pragma unroll
    for (int nt = 0; nt < 4; nt++) {
      bf16x8 b8 = *(const bf16x8*)(W2T + (colbase + nt * 16 + m) * 128 + k0);
      acc[nt] = __builtin_amdgcn_mfma_f32_16x16x32_bf16(af, b8, acc[nt], 0, 0, 0);
    }
  }
  __syncthreads();
#pragma unroll
  for (int nt = 0; nt < 4; nt++) {
    int col = colbase + nt * 16 + m;
    float b = b2[col];
#pragma unroll
    for (int r = 0; r < 4; r++)
      act[ng * 16 + quad * 4 + r][col] = f2bf(fmaxf(acc[nt][r] + b, 0.f));
  }
  __syncthreads();
  f32x4 acc3[2];
#pragma unroll
  for (int nt = 0; nt < 2; nt++) acc3[nt] = (f32x4){0,0,0,0};
#pragma unroll
  for (int kk = 0; kk < 4; kk++) {
    int k0 = kk * 32 + quad * 8;
    bf16x8 af = *(const bf16x8*)(&act[ng * 16 + m][k0]);
#pragma unroll
    for (int nt = 0; nt < 2; nt++) {
      bf16x8 b8 = *(const bf16x8*)(W3T + (half * 32 + nt * 16 + m) * 128 + k0);
      acc3[nt] = __builtin_amdgcn_mfma_f32_16x16x32_bf16(af, b8, acc3[nt], 0, 0, 0);
    }
  }
#pragma unroll
  for (int nt = 0; nt < 2; nt++) {
    int col = half * 32 + nt * 16 + m;
    float b = b3[col];
#pragma unroll
    for (int r = 0; r < 4; r++) {
      int node = nodew + quad * 4 + r;
      if (node < n) out[(long)node * 64 + col] = acc3[nt][r] + b;
    }
  }
}

extern "C" void kernel_launch(void* const* d_in, const int* in_sizes, int n_in,
                              void* d_out, int out_size, void* d_ws, size_t ws_size,
                              hipStream_t stream) {
  const float* x   = (const float*)d_in[0];
  const int*   ei  = (const int*)d_in[1];
  const float* Wl  = (const float*)d_in[2];
  const float* bl  = (const float*)d_in[3];
  const float* Wr  = (const float*)d_in[4];
  const float* br  = (const float*)d_in[5];
  const float* att = (const float*)d_in[6];
  const float* bg  = (const float*)d_in[7];
  const float* W1  = (const float*)d_in[8];
  const float* b1  = (const float*)d_in[9];
  const float* W2  = (const float*)d_in[10];
  const float* b2  = (const float*)d_in[11];
  const float* W3  = (const float*)d_in[12];
  const float* b3  = (const float*)d_in[13];
  float* out = (float*)d_out;

  const int N = in_sizes[0] / DIN;
  const int E = in_sizes[1] / 2;
  const int nbuck = (N + 255) >> 8;

  // workspace layout, every array 256B-aligned (row gathers must not split
  // cachelines). ghist and cursor0 are adjacent -> one memset clears both.
  char* ws = (char*)d_ws;
  size_t off = 0;
  auto alloc = [&](size_t bytes) {
    void* p = ws + off;
    off += (bytes + 255) & ~(size_t)255;
    return p;
  };
  int* ghist     = (int*)alloc(256 * 4);
  int* cursor0   = (int*)alloc(256 * 4);
  int* offsets   = (int*)alloc(((size_t)N + 4) * 4);
  unsigned* part = (unsigned*)alloc((size_t)E * 4);
  ushort* ssrc   = (ushort*)alloc(((size_t)E + 16) * 2);
  ushort* xlb    = (ushort*)alloc((size_t)N * DIN * 2);
  ushort* xrb    = (ushort*)alloc((size_t)N * DIN * 2);
  ushort* WlT    = (ushort*)alloc(16384 * 2);
  ushort* WrT    = (ushort*)alloc(16384 * 2);
  ushort* W1T    = (ushort*)alloc(16384 * 2);
  ushort* W2T    = (ushort*)alloc(16384 * 2);
  ushort* W3T    = (ushort*)alloc(8192 * 2);
  (void)ws_size;

  hipMemsetAsync(ghist, 0, 512 * 4, stream);   // ghist + cursor0

  int ntile = (E + PTILE - 1) / PTILE;
  cvt_hist_kernel<<<CVT_BLKS + ntile, 256, 0, stream>>>(
      Wl, Wr, W1, W2, W3, WlT, WrT, W1T, W2T, W3T, ei, ghist, E);

  int nblk32 = (N + 31) / 32;
  lin_partition_kernel<<<nblk32 + ntile, 256, 0, stream>>>(
      x, WlT, bl, WrT, br, xlb, xrb, N, nblk32, ei, part, ghist, cursor0, E);

  fine_kernel<<<nbuck, 512, 0, stream>>>(part, ghist, offsets, ssrc, N, E, nbuck);

  node_mlp_kernel<<<nblk32, 256, 0, stream>>>(
      xlb, xrb, att, bg, offsets, ssrc,
      W1T, b1, W2T, b2, W3T, b3, out, N);
}